// Round 9
// baseline (231.508 us; speedup 1.0000x reference)
//
#include <hip/hip_runtime.h>
#include <hip/hip_bf16.h>

using u16 = unsigned short;
using u32 = unsigned int;
typedef __attribute__((ext_vector_type(8))) short short8;  // 8 bf16 (4 VGPRs)
typedef __attribute__((ext_vector_type(4))) float f32x4;   // MFMA 16x16 C/D

#define MFMA16(A, B, C) __builtin_amdgcn_mfma_f32_16x16x32_bf16((A), (B), (C), 0, 0, 0)
#define QSCALE 0.18033688011112042f  // 0.125 * log2(e): softmax in exp2 domain

// ---------- bf16 helpers ----------
__device__ __forceinline__ u16 f2bf(float f) {
  union { float f; u32 i; } v; v.f = f;
  u32 x = v.i;
  return (u16)((x + 0x7fffu + ((x >> 16) & 1u)) >> 16);  // RNE
}
__device__ __forceinline__ u32 pkbf(float a, float b) {
  union { __hip_bfloat162 h; u32 u; } v;
  v.h = __float22bfloat162_rn(make_float2(a, b));
  return v.u;
}
// async global->LDS, 16B/lane; LDS dest = wave-uniform base + lane*16
__device__ __forceinline__ void gl16(const u16* g, u16* l) {
  __builtin_amdgcn_global_load_lds(
      (const __attribute__((address_space(1))) u32*)g,
      (__attribute__((address_space(3))) u32*)l, 16, 0, 0);
}

// ============================================================
// Prep A: ft fp32 -> Xbf bf16 (16384x512)
// ============================================================
__global__ __launch_bounds__(256) void conv_x(const float* __restrict__ X,
                                              u16* __restrict__ Xbf) {
  const int i = (blockIdx.x * 256 + threadIdx.x) * 8;
  float4 a = *(const float4*)(X + i);
  float4 b = *(const float4*)(X + i + 4);
  uint4 o;
  o.x = pkbf(a.x, a.y); o.y = pkbf(a.z, a.w);
  o.z = pkbf(b.x, b.y); o.w = pkbf(b.z, b.w);
  *(uint4*)(Xbf + i) = o;
}

// ============================================================
// Prep B: transpose+convert W[512][N] fp32 -> Wt[N][512] bf16
// ============================================================
__global__ __launch_bounds__(256) void transpose_w(
    const float* __restrict__ Wq, const float* __restrict__ Wo,
    u16* __restrict__ Wqt, u16* __restrict__ Wot) {
  const int z = blockIdx.z;
  if (z == 1 && blockIdx.x >= 16) return;
  const float* src = z ? Wo : Wq;
  u16* dst = z ? Wot : Wqt;
  const int ncols = z ? 512 : 1536;
  __shared__ float tile[32][33];
  const int t = threadIdx.x;
  const int kt = blockIdx.y * 32, nt = blockIdx.x * 32;
  const int r = t >> 3, c4 = (t & 7) * 4;
  float4 v = *(const float4*)(src + (size_t)(kt + r) * ncols + nt + c4);
  tile[r][c4 + 0] = v.x; tile[r][c4 + 1] = v.y;
  tile[r][c4 + 2] = v.z; tile[r][c4 + 3] = v.w;
  __syncthreads();
  uint2 p = make_uint2(pkbf(tile[c4 + 0][r], tile[c4 + 1][r]),
                       pkbf(tile[c4 + 2][r], tile[c4 + 3][r]));
  *(uint2*)(dst + (size_t)(nt + r) * 512 + kt + c4) = p;
}

// ============================================================
// Kernel 1: QKV GEMM (gl16 staging, XOR-swizzled LDS).
// Wave-level 64-col tiles are TYPE-PURE (192 = 3*64):
//   Q -> Qt[b][h][d][n] * QSCALE (uint2-packed, like V)
//   K -> Kp[b][h][n][64] via per-wave LDS transpose (uint4 stores)
//   V -> Vt[b][h][d][n] (uint2-packed)
// ============================================================
__global__ __launch_bounds__(256) void qkv_gemm(
    const u16* __restrict__ Xbf, const u16* __restrict__ Wt,
    const float* __restrict__ Bias,
    u16* __restrict__ Qt, u16* __restrict__ Kp, u16* __restrict__ Vt) {
  __shared__ u16 Xs[128][32];  // [m][k] unpadded; reused as K-epilogue scratch
  __shared__ u16 Ws[128][32];  // [n][k]
  const int t = threadIdx.x;
  const int bm = blockIdx.y * 128, bn = blockIdx.x * 128;
  const int w = t >> 6, lane = t & 63, quad = lane >> 4, l16 = lane & 15;
  const int mtb = (w >> 1) * 64, ntb = (w & 1) * 64;
  const int rr = lane >> 2;
  const int gch = ((lane & 3) ^ ((lane >> 3) & 3)) * 8;
  const int sw = (quad ^ ((l16 >> 1) & 3)) * 8;

  const u16* xg0 = Xbf + (size_t)(bm + w * 16 + rr) * 512 + gch;
  const u16* xg1 = xg0 + (size_t)64 * 512;
  const u16* wg0 = Wt + (size_t)(bn + w * 16 + rr) * 512 + gch;
  const u16* wg1 = wg0 + (size_t)64 * 512;
  u16* xl0 = &Xs[w * 16][0]; u16* xl1 = &Xs[64 + w * 16][0];
  u16* wl0 = &Ws[w * 16][0]; u16* wl1 = &Ws[64 + w * 16][0];

  f32x4 acc[4][4];
  const f32x4 z4 = {0.f, 0.f, 0.f, 0.f};
  #pragma unroll
  for (int mi = 0; mi < 4; mi++)
    #pragma unroll
    for (int ni = 0; ni < 4; ni++) acc[mi][ni] = z4;

  for (int k0 = 0; k0 < 512; k0 += 32) {
    gl16(xg0 + k0, xl0);
    gl16(xg1 + k0, xl1);
    gl16(wg0 + k0, wl0);
    gl16(wg1 + k0, wl1);
    __syncthreads();
    short8 af[4], bf4[4];
    #pragma unroll
    for (int mi = 0; mi < 4; mi++)
      af[mi] = *(const short8*)&Xs[mtb + mi * 16 + l16][sw];
    #pragma unroll
    for (int ni = 0; ni < 4; ni++)
      bf4[ni] = *(const short8*)&Ws[ntb + ni * 16 + l16][sw];
    #pragma unroll
    for (int mi = 0; mi < 4; mi++)
      #pragma unroll
      for (int ni = 0; ni < 4; ni++)
        acc[mi][ni] = MFMA16(af[mi], bf4[ni], acc[mi][ni]);
    __syncthreads();
  }

  // ---- epilogue: wave-tile cols [gcol0, gcol0+64) are one pure type ----
  const int gcol0 = bn + ntb;
  const int h = gcol0 / 192, rm = gcol0 % 192;
  const int type = rm >> 6;  // 0=Q 1=K 2=V (wave-uniform)

  if (type != 1) {  // Q or V: transposed [d][n] layout, uint2-packed
    u16* base = (type == 0) ? Qt : Vt;
    const float sc = (type == 0) ? QSCALE : 1.0f;
    #pragma unroll
    for (int ni = 0; ni < 4; ni++) {
      const float bias = Bias[gcol0 + ni * 16 + l16];
      #pragma unroll
      for (int mi = 0; mi < 4; mi++) {
        const int row0 = bm + mtb + mi * 16 + quad * 4;
        const int b = row0 >> 10, n0 = row0 & 1023;
        const size_t bho = (size_t)(b * 8 + h) * 65536;
        f32x4 a = acc[mi][ni];
        uint2 p = make_uint2(pkbf((a[0] + bias) * sc, (a[1] + bias) * sc),
                             pkbf((a[2] + bias) * sc, (a[3] + bias) * sc));
        *(uint2*)(base + bho + (size_t)(ni * 16 + l16) * 1024 + n0) = p;
      }
    }
  } else {  // K: per-wave LDS transpose (swizzled scratch) -> [n][64] uint4
    u16* scr = &Xs[0][0] + w * 1024;  // 16 rows x 64 cols bf16, per-wave
    #pragma unroll
    for (int mi = 0; mi < 4; mi++) {
      #pragma unroll
      for (int ni = 0; ni < 4; ni++) {
        const float bias = Bias[gcol0 + ni * 16 + l16];
        const int col = ni * 16 + l16;
        #pragma unroll
        for (int r = 0; r < 4; r++) {
          const int row = quad * 4 + r;
          scr[row * 64 + ((((col >> 3) ^ (row & 7)) << 3) | (col & 7))] =
              f2bf(acc[mi][ni][r] + bias);
        }
      }
      __asm__ volatile("s_waitcnt lgkmcnt(0)" ::: "memory");  // intra-wave
      const int row0 = bm + mtb + mi * 16 + l16;
      const int b = row0 >> 10, n0r = row0 & 1023;
      const size_t bho = (size_t)(b * 8 + h) * 65536;
      #pragma unroll
      for (int i = 0; i < 2; i++) {
        const int chunk = 2 * quad + i;
        uint4 v = *(const uint4*)&scr[l16 * 64 + ((chunk ^ (l16 & 7)) << 3)];
        *(uint4*)(Kp + bho + (size_t)n0r * 64 + chunk * 8) = v;
      }
      __asm__ volatile("s_waitcnt lgkmcnt(0)" ::: "memory");  // reads done
    }
  }
}

// ============================================================
// Kernel 2 v5: flash attention, S^T formulation, exp2 domain
// (Q pre-scaled by 0.125*log2e). Ps unpadded [128][128] with
// 16B-chunk XOR swizzle (conflict-free writes AND reads).
// K/V LDS-staged with reg prefetch; XCD-affinity swizzle.
// ============================================================
__global__ __launch_bounds__(512, 4) void attn_mfma(
    const u16* __restrict__ Qt, const u16* __restrict__ Kp,
    const u16* __restrict__ Vt, u16* __restrict__ ATT) {
  __shared__ u16 Ks[128][72];     // [key][d]
  __shared__ u16 Vs[64][136];     // [d][key]
  __shared__ u16 Ps[128 * 128];   // [q][key] swizzled: chunk ^= (q&7)
  const int t = threadIdx.x, w = t >> 6, lane = t & 63;
  const int quad = lane >> 4, l16 = lane & 15;
  const int bx = blockIdx.x;
  const int c = bx & 7, g = bx >> 3;
  const int qt = g & 7, u = g >> 3;
  const int bh_id = u * 8 + c;
  const int b = bh_id >> 3, h = bh_id & 7;
  const size_t bh = (size_t)bh_id * 65536;
  const u16* Qb = Qt + bh;  // [64][1024] (d-major, pre-scaled)
  const u16* Kb = Kp + bh;  // [1024][64]
  const u16* Vb = Vt + bh;  // [64][1024]
  const int q0 = qt * 128 + w * 16;

  const int kkey = t >> 2, koff = (t & 3) * 16;
  const int vrow = t >> 3, voff = (t & 7) * 16;
  const u16* Kg = Kb + (size_t)kkey * 64 + koff;
  const u16* Vg = Vb + (size_t)vrow * 1024 + voff;

  // Q frags from transposed layout: one-time 16 scalar loads
  short8 qf[2];
  #pragma unroll
  for (int ks = 0; ks < 2; ks++) {
    short8 v;
    #pragma unroll
    for (int j = 0; j < 8; j++)
      v[j] = (short)Qb[(size_t)(ks * 32 + quad * 8 + j) * 1024 + q0 + l16];
    qf[ks] = v;
  }

  float m_ = -1e30f, l_ = 0.f;
  f32x4 Of[4];
  const f32x4 z4 = {0.f, 0.f, 0.f, 0.f};
  #pragma unroll
  for (int ni = 0; ni < 4; ni++) Of[ni] = z4;

  uint4 kr0 = *(const uint4*)(Kg);
  uint4 kr1 = *(const uint4*)(Kg + 8);
  uint4 vr0 = *(const uint4*)(Vg);
  uint4 vr1 = *(const uint4*)(Vg + 8);

  for (int kt = 0; kt < 8; kt++) {
    __syncthreads();
    *(uint4*)&Ks[kkey][koff]     = kr0;
    *(uint4*)&Ks[kkey][koff + 8] = kr1;
    *(uint4*)&Vs[vrow][voff]     = vr0;
    *(uint4*)&Vs[vrow][voff + 8] = vr1;
    if (kt < 7) {
      kr0 = *(const uint4*)(Kg + (kt + 1) * 8192);
      kr1 = *(const uint4*)(Kg + (kt + 1) * 8192 + 8);
      vr0 = *(const uint4*)(Vg + (kt + 1) * 128);
      vr1 = *(const uint4*)(Vg + (kt + 1) * 128 + 8);
    }
    __syncthreads();

    // ---- S^T tiles: D[m=key][n=q] (16 MFMA) ----
    f32x4 s[8];
    #pragma unroll
    for (int nt = 0; nt < 8; nt++) s[nt] = z4;
    #pragma unroll
    for (int nt = 0; nt < 8; nt++) {
      short8 k0f = *(const short8*)&Ks[nt * 16 + l16][quad * 8];
      short8 k1f = *(const short8*)&Ks[nt * 16 + l16][quad * 8 + 32];
      s[nt] = MFMA16(k0f, qf[0], s[nt]);
      s[nt] = MFMA16(k1f, qf[1], s[nt]);
    }
    // ---- softmax (exp2 domain): lane owns query q0+l16 ----
    float mloc = -1e30f;
    #pragma unroll
    for (int nt = 0; nt < 8; nt++)
      #pragma unroll
      for (int r = 0; r < 4; r++) mloc = fmaxf(mloc, s[nt][r]);
    mloc = fmaxf(mloc, __shfl_xor(mloc, 16));
    mloc = fmaxf(mloc, __shfl_xor(mloc, 32));
    const float mnew = fmaxf(m_, mloc);
    const float alpha = exp2f(m_ - mnew);
    float rs = 0.f;
    #pragma unroll
    for (int nt = 0; nt < 8; nt++) {
      float p0 = exp2f(s[nt][0] - mnew), p1 = exp2f(s[nt][1] - mnew);
      float p2 = exp2f(s[nt][2] - mnew), p3 = exp2f(s[nt][3] - mnew);
      rs += (p0 + p1) + (p2 + p3);
      const int physW = (2 * nt + (quad >> 1)) ^ (l16 & 7);
      *(uint2*)&Ps[(w * 16 + l16) * 128 + (physW << 3) + (quad & 1) * 4] =
          make_uint2(pkbf(p0, p1), pkbf(p2, p3));
    }
    rs += __shfl_xor(rs, 16);
    rs += __shfl_xor(rs, 32);
    l_ = l_ * alpha + rs;
    m_ = mnew;
    float av[4];
    #pragma unroll
    for (int r = 0; r < 4; r++) av[r] = __shfl(alpha, quad * 4 + r);
    #pragma unroll
    for (int ni = 0; ni < 4; ni++)
      #pragma unroll
      for (int r = 0; r < 4; r++) Of[ni][r] *= av[r];
    // ---- O += P V (16 MFMA) ----
    #pragma unroll
    for (int ks = 0; ks < 4; ks++) {
      const int physR = (4 * ks + quad) ^ (l16 & 7);
      short8 pa = *(const short8*)&Ps[(w * 16 + l16) * 128 + (physR << 3)];
      #pragma unroll
      for (int ni = 0; ni < 4; ni++) {
        short8 vf = *(const short8*)&Vs[ni * 16 + l16][ks * 32 + quad * 8];
        Of[ni] = MFMA16(pa, vf, Of[ni]);
      }
    }
  }
  // ---- epilogue ----
  float lv[4];
  #pragma unroll
  for (int r = 0; r < 4; r++) lv[r] = __shfl(l_, quad * 4 + r);
  #pragma unroll
  for (int r = 0; r < 4; r++) {
    const float inv = 1.0f / lv[r];
    const int row = b * 1024 + q0 + quad * 4 + r;
    #pragma unroll
    for (int ni = 0; ni < 4; ni++)
      ATT[(size_t)row * 512 + h * 64 + ni * 16 + l16] = f2bf(Of[ni][r] * inv);
  }
}

// ============================================================
// Kernel 3: OUT = ATT(bf16) @ Wout^T + bias + ft(f32) -> f32
// ============================================================
__global__ __launch_bounds__(256) void out_proj(
    const u16* __restrict__ A, const u16* __restrict__ Wt,
    const float* __restrict__ Bias, const float* __restrict__ FT,
    float* __restrict__ OUT) {
  __shared__ u16 As[128][32];
  __shared__ u16 Ws[128][32];
  const int t = threadIdx.x;
  const int bm = blockIdx.y * 128, bn = blockIdx.x * 128;
  const int w = t >> 6, lane = t & 63, quad = lane >> 4, l16 = lane & 15;
  const int mtb = (w >> 1) * 64, ntb = (w & 1) * 64;
  const int rr = lane >> 2;
  const int gch = ((lane & 3) ^ ((lane >> 3) & 3)) * 8;
  const int sw = (quad ^ ((l16 >> 1) & 3)) * 8;

  const u16* ag0 = A + (size_t)(bm + w * 16 + rr) * 512 + gch;
  const u16* ag1 = ag0 + (size_t)64 * 512;
  const u16* wg0 = Wt + (size_t)(bn + w * 16 + rr) * 512 + gch;
  const u16* wg1 = wg0 + (size_t)64 * 512;
  u16* al0 = &As[w * 16][0]; u16* al1 = &As[64 + w * 16][0];
  u16* wl0 = &Ws[w * 16][0]; u16* wl1 = &Ws[64 + w * 16][0];

  f32x4 acc[4][4];
  const f32x4 z4 = {0.f, 0.f, 0.f, 0.f};
  #pragma unroll
  for (int mi = 0; mi < 4; mi++)
    #pragma unroll
    for (int ni = 0; ni < 4; ni++) acc[mi][ni] = z4;

  for (int k0 = 0; k0 < 512; k0 += 32) {
    gl16(ag0 + k0, al0);
    gl16(ag1 + k0, al1);
    gl16(wg0 + k0, wl0);
    gl16(wg1 + k0, wl1);
    __syncthreads();
    short8 af[4], bf4[4];
    #pragma unroll
    for (int mi = 0; mi < 4; mi++)
      af[mi] = *(const short8*)&As[mtb + mi * 16 + l16][sw];
    #pragma unroll
    for (int ni = 0; ni < 4; ni++)
      bf4[ni] = *(const short8*)&Ws[ntb + ni * 16 + l16][sw];
    #pragma unroll
    for (int mi = 0; mi < 4; mi++)
      #pragma unroll
      for (int ni = 0; ni < 4; ni++)
        acc[mi][ni] = MFMA16(af[mi], bf4[ni], acc[mi][ni]);
    __syncthreads();
  }

  #pragma unroll
  for (int ni = 0; ni < 4; ni++) {
    const int g = bn + ntb + ni * 16;
    const float bias = Bias[g + l16];
    #pragma unroll
    for (int mi = 0; mi < 4; mi++) {
      const int row0 = bm + mtb + mi * 16 + quad * 4;
      #pragma unroll
      for (int r = 0; r < 4; r++) {
        const size_t idx = (size_t)(row0 + r) * 512 + g + l16;
        OUT[idx] = acc[mi][ni][r] + bias + FT[idx];
      }
    }
  }
}

// ============================================================
extern "C" void kernel_launch(void* const* d_in, const int* in_sizes, int n_in,
                              void* d_out, int out_size, void* d_ws, size_t ws_size,
                              hipStream_t stream) {
  const float* ft    = (const float*)d_in[0];  // [16][1024][512] f32
  const float* w_qkv = (const float*)d_in[1];  // [512][1536]   f32
  const float* b_qkv = (const float*)d_in[2];  // [1536]        f32
  const float* w_out = (const float*)d_in[3];  // [512][512]    f32
  const float* b_out = (const float*)d_in[4];  // [512]         f32
  float* out = (float*)d_out;                  // [16][1024][512] f32

  char* p = (char*)d_ws;
  u16* Xbf    = (u16*)(p);                              // 16,777,216
  u16* ATT    = Xbf;                                    // alias (Xbf dead)
  u16* Wqkv_t = (u16*)(p + 16777216);                   //  1,572,864
  u16* Wout_t = (u16*)(p + 18350080);                   //    524,288
  u16* Qt     = (u16*)(p + 18874368);                   // 16,777,216 [b][h][d][n], pre-scaled
  u16* Kp     = (u16*)(p + 35651584);                   // 16,777,216 [b][h][n][64]
  u16* Vt     = (u16*)(p + 52428800);                   // 16,777,216 [b][h][d][n]

  conv_x     <<<4096, 256, 0, stream>>>(ft, Xbf);
  transpose_w<<<dim3(48, 16, 2), 256, 0, stream>>>(w_qkv, w_out, Wqkv_t, Wout_t);
  qkv_gemm   <<<dim3(12, 128), 256, 0, stream>>>(Xbf, Wqkv_t, b_qkv, Qt, Kp, Vt);
  attn_mfma  <<<dim3(1024), 512, 0, stream>>>(Qt, Kp, Vt, ATT);
  out_proj   <<<dim3(4, 128), 256, 0, stream>>>(ATT, Wout_t, b_out, ft, out);
}